// Round 5
// baseline (840.424 us; speedup 1.0000x reference)
//
#include <hip/hip_runtime.h>
#include <math.h>

#define HW 65536
#define NC 10
#define NT 12
#define LAMBDA_F 0.05f
#define PI_F 3.14159265358979323846f
// XOR-swizzle for wave-private LDS fft scratch
#define SWZ(i) ((i) ^ ((i) >> 4))

__device__ __forceinline__ float2 cadd(float2 a, float2 b){ return make_float2(a.x+b.x, a.y+b.y); }
__device__ __forceinline__ float2 csub(float2 a, float2 b){ return make_float2(a.x-b.x, a.y-b.y); }
__device__ __forceinline__ float2 cmul(float2 a, float2 b){ return make_float2(a.x*b.x-a.y*b.y, a.x*b.y+a.y*b.x); }
// conj(a)*b
__device__ __forceinline__ float2 cmulj(float2 a, float2 b){ return make_float2(a.x*b.x+a.y*b.y, a.x*b.y-a.y*b.x); }
__device__ __forceinline__ float2 cscale(float2 a, float s){ return make_float2(a.x*s, a.y*s); }

template<int SIGN>
__device__ __forceinline__ void radix4_nt(float2& a0, float2& a1, float2& a2, float2& a3){
  float2 t0=cadd(a0,a2), t1=csub(a0,a2), t2=cadd(a1,a3), t3=csub(a1,a3);
  float2 t3r;
  if constexpr (SIGN < 0) t3r = make_float2(t3.y, -t3.x); else t3r = make_float2(-t3.y, t3.x);
  a0=cadd(t0,t2); a1=cadd(t1,t3r); a2=csub(t0,t2); a3=csub(t1,t3r);
}

// w = exp(-2*pi*i*e/256) held in registers; conj applied for SIGN=+1.
template<int SIGN>
__device__ __forceinline__ void radix4_tw(float2& a0, float2& a1, float2& a2, float2& a3, float2 w){
  if constexpr (SIGN > 0) w.y = -w.y;
  float2 w2 = cmul(w, w);
  float2 w3 = cmul(w, w2);
  a1 = cmul(a1, w); a2 = cmul(a2, w2); a3 = cmul(a3, w3);
  radix4_nt<SIGN>(a0, a1, a2, a3);
}

__device__ __forceinline__ float2 twf(int e){
  float s, c;
  __sincosf(-2.0f*PI_F*(float)e*(1.0f/256.0f), &s, &c);
  return make_float2(c, s);
}

// 256-pt Stockham radix-4 FFT, natural order in/out, unnormalized.
// b0/b1 must be private to the calling wave (64 lanes). No fences: plain ds
// ops on the same array are kept in order by the compiler (may-alias), while
// DIFFERENT arrays (other streams' scratch) may be freely interleaved -> ILP.
// wA=twf(16*(j&3)), wB=twf(4*(j&15)), wC=twf(j) precomputed in registers.
template<int SIGN>
__device__ __forceinline__ void fft256(float2* b0, float2* b1, int j,
                                       float2 wA, float2 wB, float2 wC,
                                       float2& x0, float2& x1, float2& x2, float2& x3){
  radix4_nt<SIGN>(x0,x1,x2,x3);
  b0[SWZ(4*j)]=x0; b0[SWZ(4*j+1)]=x1; b0[SWZ(4*j+2)]=x2; b0[SWZ(4*j+3)]=x3;
  x0=b0[SWZ(j)]; x1=b0[SWZ(j+64)]; x2=b0[SWZ(j+128)]; x3=b0[SWZ(j+192)];
  radix4_tw<SIGN>(x0,x1,x2,x3, wA);
  { int i=((j>>2)<<4)+(j&3); b1[SWZ(i)]=x0; b1[SWZ(i+4)]=x1; b1[SWZ(i+8)]=x2; b1[SWZ(i+12)]=x3; }
  x0=b1[SWZ(j)]; x1=b1[SWZ(j+64)]; x2=b1[SWZ(j+128)]; x3=b1[SWZ(j+192)];
  radix4_tw<SIGN>(x0,x1,x2,x3, wB);
  { int i=((j>>4)<<6)+(j&15); b0[SWZ(i)]=x0; b0[SWZ(i+16)]=x1; b0[SWZ(i+32)]=x2; b0[SWZ(i+48)]=x3; }
  x0=b0[SWZ(j)]; x1=b0[SWZ(j+64)]; x2=b0[SWZ(j+128)]; x3=b0[SWZ(j+192)];
  radix4_tw<SIGN>(x0,x1,x2,x3, wC);
}

// Reconstruct alpha_{it-1}, beta_{it-1} from reduced scalars (verified r3).
// scal: [0]=rs0 ; per k: [8+8k]=pAp.re [+1]=pAp.im [+2]=rAp.re [+3]=rAp.im [+4]=|Ap|^2
__device__ __forceinline__ void cg_scalars(const float* __restrict__ scal, int it,
                                           float& a_re, float& a_im, float& beta){
  float rs = scal[0]; a_re = 0.f; a_im = 0.f; beta = 0.f;
  for (int k = 0; k < it; k++){
    float pr = scal[8+8*k+0], pi = scal[8+8*k+1];
    float rr_ = scal[8+8*k+2], ri_ = scal[8+8*k+3];
    float aa = scal[8+8*k+4];
    float den = pr*pr + pi*pi;
    a_re =  rs*pr/den;
    a_im = -rs*pi/den;
    float re_ = a_re*rr_ - a_im*ri_;   // Re(alpha * rAp)
    float rs_next = rs - 2.0f*re_ + (a_re*a_re + a_im*a_im)*aa;
    beta = rs_next/rs;
    rs = rs_next;
  }
}

// ---------- S0: W9 precompute + g = D*sum_t conj(L) y (into bufB) + scal zero
__global__ __launch_bounds__(256) void k_setup(const float* __restrict__ mask,
                                               const float2* __restrict__ Lt,
                                               const float2* __restrict__ y,
                                               float* __restrict__ W9,
                                               float2* __restrict__ bufB,
                                               float* __restrict__ scal){
  int tid = threadIdx.x;
  int u = blockIdx.x;
  if (u == 0 && tid < 128) scal[tid] = 0.0f;
  if (u < 256){
    int kx = u, ky = tid;
    int mx = (kx + 128) & 255, my = (ky + 128) & 255;
    float d0=0.f,d1=0.f,d2=0.f;
    float2 o01=make_float2(0,0), o02=make_float2(0,0), o12=make_float2(0,0);
    for (int t = 0; t < NT; t++){
      float m = mask[t*HW + my*256 + mx];
      float2 l0 = Lt[t*3+0], l1 = Lt[t*3+1], l2 = Lt[t*3+2];
      d0 += m*(l0.x*l0.x + l0.y*l0.y);
      d1 += m*(l1.x*l1.x + l1.y*l1.y);
      d2 += m*(l2.x*l2.x + l2.y*l2.y);
      o01 = cadd(o01, cscale(cmulj(l0,l1), m));
      o02 = cadd(o02, cscale(cmulj(l0,l2), m));
      o12 = cadd(o12, cscale(cmulj(l1,l2), m));
    }
    const float nrm = 1.0f/65536.0f;
    int idx = kx*256 + ky;
    W9[idx]      = d0*nrm;  W9[idx+HW]   = d1*nrm;  W9[idx+2*HW] = d2*nrm;
    W9[idx+3*HW] = o01.x*nrm; W9[idx+4*HW] = o01.y*nrm;
    W9[idx+5*HW] = o02.x*nrm; W9[idx+6*HW] = o02.y*nrm;
    W9[idx+7*HW] = o12.x*nrm; W9[idx+8*HW] = o12.y*nrm;
  } else {
    int idx = (u-256)*256 + tid;
    int c = idx >> 16, pix = idx & (HW-1);
    int xx = pix & 255, yy2 = pix >> 8;
    float sg = ((xx + yy2) & 1) ? -1.0f : 1.0f;
    float2 a0=make_float2(0,0), a1=make_float2(0,0), a2=make_float2(0,0);
    for (int t = 0; t < NT; t++){
      float2 yv = y[((size_t)(t*NC + c))*HW + pix];
      a0 = cadd(a0, cmulj(Lt[t*3+0], yv));
      a1 = cadd(a1, cmulj(Lt[t*3+1], yv));
      a2 = cadd(a2, cmulj(Lt[t*3+2], yv));
    }
    bufB[((size_t)(c*3+0))*HW + pix] = cscale(a0, sg);
    bufB[((size_t)(c*3+1))*HW + pix] = cscale(a1, sg);
    bufB[((size_t)(c*3+2))*HW + pix] = cscale(a2, sg);
  }
}

// ---------- setup row IFFT (-1): bufB row-major -> bufA transposed [pl][kx][y]
__global__ __launch_bounds__(256) void k_rows_plain(const float2* __restrict__ src,
                                                    float2* __restrict__ dst){
  __shared__ float2 tile[8][256];
  __shared__ float2 sc2[8][256];
  int tid = threadIdx.x, g = tid >> 6, j = tid & 63;
  float2 wA = twf((j&3)<<4), wB = twf((j&15)<<2), wC = twf(j);
  int pl = blockIdx.y, ri = blockIdx.x;
  const float2* s = src + (size_t)pl*HW;
  #pragma unroll
  for (int rr = 0; rr < 2; rr++){
    int lr = g + rr*4, row = ri*8 + lr;
    const float2* sr = s + row*256;
    float2 x0=sr[j], x1=sr[j+64], x2=sr[j+128], x3=sr[j+192];
    fft256<-1>(tile[lr], sc2[lr], j, wA,wB,wC, x0,x1,x2,x3);
    tile[lr][j]=x0; tile[lr][j+64]=x1; tile[lr][j+128]=x2; tile[lr][j+192]=x3;
  }
  __syncthreads();
  float2* dT = dst + (size_t)pl*HW;
  int yo2 = (tid&3)*2, kxo = tid>>2;
  #pragma unroll
  for (int kb = 0; kb < 4; kb++){
    int kx = kb*64 + kxo;
    float2 a = tile[yo2][kx], b = tile[yo2+1][kx];
    *(float4*)(dT + (size_t)kx*256 + ri*8 + yo2) = make_float4(a.x,a.y,b.x,b.y);
  }
}

// ---------- setup col IFFT (-1): bufA [pl][kx][y] contiguous -> bufB row-major
__global__ __launch_bounds__(256) void k_cols_plain(const float2* __restrict__ src,
                                                    float2* __restrict__ dst){
  __shared__ float2 tile[4][256];
  __shared__ float2 sc2[4][256];
  int tid = threadIdx.x, g = tid >> 6, j = tid & 63;
  float2 wA = twf((j&3)<<4), wB = twf((j&15)<<2), wC = twf(j);
  int pl = blockIdx.y, kg = blockIdx.x;
  int kx = kg*4 + g;
  const float2* col = src + (size_t)pl*HW + (size_t)kx*256;
  float2 x0=col[j], x1=col[j+64], x2=col[j+128], x3=col[j+192];
  fft256<-1>(tile[g], sc2[g], j, wA,wB,wC, x0,x1,x2,x3);
  tile[g][j]=x0; tile[g][j+64]=x1; tile[g][j+128]=x2; tile[g][j+192]=x3;
  __syncthreads();
  float2* d = dst + (size_t)pl*HW;
  int kxo2 = (tid&1)*2, yy = tid>>1;
  #pragma unroll
  for (int yb = 0; yb < 2; yb++){
    int yc = yb*128 + yy;
    float2 a = tile[kxo2][yc], b = tile[kxo2+1][yc];
    *(float4*)(d + (size_t)yc*256 + kg*4 + kxo2) = make_float4(a.x,a.y,b.x,b.y);
  }
}

// ---------- b = D * sum_c conj(S_c) * bufB + lambda*mo ; p=r=b ; z=0 ; rs0
__global__ __launch_bounds__(256) void k_compute_b(const float2* __restrict__ A,
                                                   const float2* __restrict__ sens,
                                                   const float2* __restrict__ mo,
                                                   float2* __restrict__ p,
                                                   float2* __restrict__ r,
                                                   float2* __restrict__ z,
                                                   float* __restrict__ scal){
  __shared__ float red[4];
  int idx = blockIdx.x*256 + threadIdx.x;
  int s = idx >> 16, pix = idx & (HW-1);
  int xx = pix & 255, yy = pix >> 8;
  float sg = ((xx + yy) & 1) ? -1.0f : 1.0f;
  float2 accv = make_float2(0,0);
  for (int c = 0; c < NC; c++)
    accv = cadd(accv, cmulj(sens[(size_t)c*HW + pix], A[((size_t)(c*3+s))*HW + pix]));
  float2 b = cadd(cscale(accv, sg), cscale(mo[idx], LAMBDA_F));
  p[idx] = b; r[idx] = b; z[idx] = make_float2(0,0);
  float part = b.x*b.x + b.y*b.y;
  for (int off = 32; off; off >>= 1) part += __shfl_down(part, off);
  int j = threadIdx.x & 63, w = threadIdx.x >> 6;
  if (j == 0) red[w] = part;
  __syncthreads();
  if (threadIdx.x == 0) atomicAdd(&scal[0], red[0]+red[1]+red[2]+red[3]);
}

// ---------- A: fused CG update (z,r,p) + sens-mult + row FFT (+1) -> bufA (T)
// it==0: pv = pprev (=b). it>0: alpha/beta reconstructed from scal;
// rnew = rprev - alpha*Ap; pv = rnew + beta*pprev; c==0 blocks persist
// rnew/pv and z += alpha*pprev.
__global__ __launch_bounds__(256) void k_rows_op(const float2* __restrict__ rprev,
                                                 const float2* __restrict__ pprev,
                                                 const float2* __restrict__ Apb,
                                                 float2* __restrict__ pout,
                                                 float2* __restrict__ rout,
                                                 float2* __restrict__ z,
                                                 const float2* __restrict__ sens,
                                                 float2* __restrict__ dst,
                                                 const float* __restrict__ scal, int iter){
  __shared__ float2 tile[8][256];
  __shared__ float2 sc2[8][256];
  int tid = threadIdx.x, g = tid >> 6, j = tid & 63;
  float2 wA = twf((j&3)<<4), wB = twf((j&15)<<2), wC = twf(j);
  int pl = blockIdx.y, ri = blockIdx.x;
  int c = pl/3, sp = pl - 3*c;
  const float2* Sp = sens + (size_t)c*HW;
  float a_re=0.f, a_im=0.f, beta=0.f;
  if (iter > 0) cg_scalars(scal, iter, a_re, a_im, beta);
  #pragma unroll
  for (int rr = 0; rr < 2; rr++){
    int lr = g + rr*4, row = ri*8 + lr;
    int base = row*256;
    size_t pb = (size_t)sp*HW + base;
    float2 pv[4];
    if (iter == 0){
      pv[0]=pprev[pb+j]; pv[1]=pprev[pb+j+64]; pv[2]=pprev[pb+j+128]; pv[3]=pprev[pb+j+192];
    } else {
      #pragma unroll
      for (int q = 0; q < 4; q++){
        int x = j + 64*q;
        float2 pe = pprev[pb+x], re_ = rprev[pb+x], ae = Apb[pb+x];
        float2 rnew = make_float2(re_.x - (a_re*ae.x - a_im*ae.y),
                                  re_.y - (a_re*ae.y + a_im*ae.x));
        pv[q] = make_float2(rnew.x + beta*pe.x, rnew.y + beta*pe.y);
        if (c == 0){
          rout[pb+x] = rnew;
          pout[pb+x] = pv[q];
          float2 ze = z[pb+x];
          z[pb+x] = make_float2(ze.x + a_re*pe.x - a_im*pe.y,
                                ze.y + a_re*pe.y + a_im*pe.x);
        }
      }
    }
    float2 x0 = cmul(Sp[base+j],     pv[0]);
    float2 x1 = cmul(Sp[base+j+64],  pv[1]);
    float2 x2 = cmul(Sp[base+j+128], pv[2]);
    float2 x3 = cmul(Sp[base+j+192], pv[3]);
    fft256<1>(tile[lr], sc2[lr], j, wA,wB,wC, x0,x1,x2,x3);
    tile[lr][j]=x0; tile[lr][j+64]=x1; tile[lr][j+128]=x2; tile[lr][j+192]=x3;
  }
  __syncthreads();
  float2* dT = dst + (size_t)pl*HW;
  int yo2 = (tid&3)*2, kxo = tid>>2;
  #pragma unroll
  for (int kb = 0; kb < 4; kb++){
    int kx = kb*64 + kxo;
    float2 a = tile[yo2][kx], b = tile[yo2+1][kx];
    *(float4*)(dT + (size_t)kx*256 + ri*8 + yo2) = make_float4(a.x,a.y,b.x,b.y);
  }
}

// ---------- B: col FFT(+1) -> 3x3 W -> col IFFT(-1); bufA contiguous -> bufB row-major
__global__ __launch_bounds__(256) void k_cols_W(const float2* __restrict__ src,
                                                float2* __restrict__ dst,
                                                const float* __restrict__ W9){
  __shared__ float2 tile[12][256];   // per-s b0, doubles as out-staging
  __shared__ float2 sc2[12][256];    // per-s b1 -> 3-stream ILP
  int tid = threadIdx.x, g = tid >> 6, j = tid & 63;
  float2 wA = twf((j&3)<<4), wB = twf((j&15)<<2), wC = twf(j);
  int kg = blockIdx.x, c = blockIdx.y;
  int kx = kg*4 + g;
  float2 X[3][4];
  #pragma unroll
  for (int s = 0; s < 3; s++){
    const float2* col = src + ((size_t)(c*3+s))*HW + (size_t)kx*256;
    float2 x0=col[j], x1=col[j+64], x2=col[j+128], x3=col[j+192];
    fft256<1>(tile[s*4+g], sc2[s*4+g], j, wA,wB,wC, x0,x1,x2,x3);
    X[s][0]=x0; X[s][1]=x1; X[s][2]=x2; X[s][3]=x3;
  }
  float2 U[3][4];
  #pragma unroll
  for (int q = 0; q < 4; q++){
    int wi = kx*256 + j + 64*q;
    float d0 = W9[wi], d1 = W9[wi+HW], d2 = W9[wi+2*HW];
    float2 o01 = make_float2(W9[wi+3*HW], W9[wi+4*HW]);
    float2 o02 = make_float2(W9[wi+5*HW], W9[wi+6*HW]);
    float2 o12 = make_float2(W9[wi+7*HW], W9[wi+8*HW]);
    float2 v0 = X[0][q], v1 = X[1][q], v2 = X[2][q];
    U[0][q] = cadd(cadd(cscale(v0,d0), cmul(o01,v1)), cmul(o02,v2));
    U[1][q] = cadd(cadd(cmulj(o01,v0), cscale(v1,d1)), cmul(o12,v2));
    U[2][q] = cadd(cadd(cmulj(o02,v0), cmulj(o12,v1)), cscale(v2,d2));
  }
  #pragma unroll
  for (int s = 0; s < 3; s++){
    float2 x0=U[s][0], x1=U[s][1], x2=U[s][2], x3=U[s][3];
    fft256<-1>(tile[s*4+g], sc2[s*4+g], j, wA,wB,wC, x0,x1,x2,x3);
    tile[s*4+g][j]=x0; tile[s*4+g][j+64]=x1; tile[s*4+g][j+128]=x2; tile[s*4+g][j+192]=x3;
  }
  __syncthreads();
  int kxo2 = (tid&1)*2, yy = tid>>1;
  for (int s = 0; s < 3; s++){
    float2* d = dst + ((size_t)(c*3+s))*HW;
    #pragma unroll
    for (int yb = 0; yb < 2; yb++){
      int yc = yb*128 + yy;
      float2 a = tile[s*4+kxo2][yc], b = tile[s*4+kxo2+1][yc];
      *(float4*)(d + (size_t)yc*256 + kg*4 + kxo2) = make_float4(a.x,a.y,b.x,b.y);
    }
  }
}

// ---------- C: row IFFT(-1) + conj(S) combine + lambda*p -> Ap; reduce pAp,rAp,|Ap|^2
__global__ __launch_bounds__(256) void k_rows_acc(const float2* __restrict__ Bp,
                                                  const float2* __restrict__ sens,
                                                  const float2* __restrict__ p,
                                                  const float2* __restrict__ r,
                                                  float2* __restrict__ Ap,
                                                  float* __restrict__ scal, int iter){
  __shared__ float2 b0[8][256], b1[8][256];   // 2-deep ping-pong per wave
  __shared__ float2 acc[4][256];
  __shared__ float red5[4][5];
  int tid = threadIdx.x, g = tid >> 6, j = tid & 63;
  float2 wA = twf((j&3)<<4), wB = twf((j&15)<<2), wC = twf(j);
  int row = blockIdx.x, s = blockIdx.y;
  float2 zz = make_float2(0,0);
  float2 a0=zz, a1=zz, a2=zz, a3=zz;
  #pragma unroll
  for (int cc = 0; cc < 3; cc++){
    int c = cc*4 + g;
    if (c < NC){
      const float2* src = Bp + ((size_t)(c*3+s))*HW + row*256;
      float2 x0=src[j], x1=src[j+64], x2=src[j+128], x3=src[j+192];
      fft256<-1>(b0[(cc&1)*4+g], b1[(cc&1)*4+g], j, wA,wB,wC, x0,x1,x2,x3);
      const float2* Sc = sens + (size_t)c*HW + row*256;
      a0 = cadd(a0, cmulj(Sc[j],     x0));
      a1 = cadd(a1, cmulj(Sc[j+64],  x1));
      a2 = cadd(a2, cmulj(Sc[j+128], x2));
      a3 = cadd(a3, cmulj(Sc[j+192], x3));
    }
  }
  acc[g][j]=a0; acc[g][j+64]=a1; acc[g][j+128]=a2; acc[g][j+192]=a3;
  __syncthreads();
  int k = tid;
  size_t ob = (size_t)s*HW + row*256 + k;
  float2 a = cadd(cadd(acc[0][k], acc[1][k]), cadd(acc[2][k], acc[3][k]));
  float2 pv = p[ob];
  float2 ap = cadd(a, cscale(pv, LAMBDA_F));
  Ap[ob] = ap;
  float2 rv = r[ob];
  float s0 = pv.x*ap.x + pv.y*ap.y;   // pAp.re
  float s1 = pv.x*ap.y - pv.y*ap.x;   // pAp.im
  float s2 = rv.x*ap.x + rv.y*ap.y;   // rAp.re
  float s3 = rv.x*ap.y - rv.y*ap.x;   // rAp.im
  float s4 = ap.x*ap.x + ap.y*ap.y;   // |Ap|^2
  for (int off = 32; off; off >>= 1){
    s0 += __shfl_down(s0, off); s1 += __shfl_down(s1, off);
    s2 += __shfl_down(s2, off); s3 += __shfl_down(s3, off);
    s4 += __shfl_down(s4, off);
  }
  if (j == 0){ red5[g][0]=s0; red5[g][1]=s1; red5[g][2]=s2; red5[g][3]=s3; red5[g][4]=s4; }
  __syncthreads();
  if (tid == 0){
    atomicAdd(&scal[8+8*iter+0], red5[0][0]+red5[1][0]+red5[2][0]+red5[3][0]);
    atomicAdd(&scal[8+8*iter+1], red5[0][1]+red5[1][1]+red5[2][1]+red5[3][1]);
    atomicAdd(&scal[8+8*iter+2], red5[0][2]+red5[1][2]+red5[2][2]+red5[3][2]);
    atomicAdd(&scal[8+8*iter+3], red5[0][3]+red5[1][3]+red5[2][3]+red5[3][3]);
    atomicAdd(&scal[8+8*iter+4], red5[0][4]+red5[1][4]+red5[2][4]+red5[3][4]);
  }
}

// ---------- final: z += alpha_9 * p_9
__global__ __launch_bounds__(256) void k_zfin(float2* __restrict__ z,
                                              const float2* __restrict__ p9,
                                              const float* __restrict__ scal){
  float a_re, a_im, beta;
  cg_scalars(scal, 10, a_re, a_im, beta);
  int idx = blockIdx.x*256 + threadIdx.x;
  float2 pe = p9[idx], ze = z[idx];
  z[idx] = make_float2(ze.x + a_re*pe.x - a_im*pe.y,
                       ze.y + a_re*pe.y + a_im*pe.x);
}

extern "C" void kernel_launch(void* const* d_in, const int* in_sizes, int n_in,
                              void* d_out, int out_size, void* d_ws, size_t ws_size,
                              hipStream_t stream){
  const float2* y    = (const float2*)d_in[0];
  const float2* mo   = (const float2*)d_in[1];
  const float2* sens = (const float2*)d_in[2];
  const float2* Lt   = (const float2*)d_in[3];
  const float*  mask = (const float*)d_in[4];

  float* w = (float*)d_ws;
  float*  scal = w;                                  // 128 floats
  float*  W9   = w + 128;                            // 9*HW floats
  float2* bufA = (float2*)(w + 128 + 9*HW);          // 30 planes (transposed k-space)
  float2* bufB = bufA + (size_t)30*HW;               // 30 planes (row-major)
  float2* p0   = bufB + (size_t)30*HW;
  float2* p1   = p0 + (size_t)3*HW;
  float2* r0   = p1 + (size_t)3*HW;
  float2* r1   = r0 + (size_t)3*HW;
  float2* Ap   = r1 + (size_t)3*HW;
  float2* z    = (float2*)d_out;

  // setup
  k_setup<<<2816, 256, 0, stream>>>(mask, Lt, y, W9, bufB, scal);
  k_rows_plain<<<dim3(32, 30), 256, 0, stream>>>(bufB, bufA);
  k_cols_plain<<<dim3(64, 30), 256, 0, stream>>>(bufA, bufB);
  k_compute_b<<<768, 256, 0, stream>>>(bufB, sens, mo, p0, r0, z, scal);

  // CG iterations: 3 kernels each (update fused into rows_op)
  for (int it = 0; it < 10; it++){
    float2* pprev = (it == 0) ? p0 : ((it & 1) ? p0 : p1);
    float2* rprev = (it == 0) ? r0 : ((it & 1) ? r0 : r1);
    float2* pw = (it & 1) ? p1 : p0;   // p_it
    float2* rw = (it & 1) ? r1 : r0;   // r_it
    k_rows_op<<<dim3(32, 30), 256, 0, stream>>>(rprev, pprev, Ap, pw, rw, z, sens, bufA, scal, it);
    k_cols_W<<<dim3(64, 10), 256, 0, stream>>>(bufA, bufB, W9);
    k_rows_acc<<<dim3(256, 3), 256, 0, stream>>>(bufB, sens, pw, rw, Ap, scal, it);
  }
  k_zfin<<<768, 256, 0, stream>>>(z, p1, scal);
}